// Round 6
// baseline (42.742 us; speedup 1.0000x reference)
//
#include <hip/hip_runtime.h>
#include <hip/hip_fp16.h>

// Joint bilateral filter, K=5, zero padding, fp16 LDS staging + f32 compute.
// t: (2,3,720,1280) f32 guide; v: (2,2,720,1280) f32 flow; out: (2,2,720,1280) f32
// coeff = max(0.875 - 50*sum_c (t_c - ts_c)^2, 0); out = sum(vs*coeff)/sum(coeff)
//
// Block = 256 threads -> output tile 128 cols x 8 rows. Inputs staged into LDS
// as __half (16,320 B/block -> 8 blocks/CU resident, 32 waves/CU; DS bytes
// halved vs f32 staging). Tap math in f32; half operands feed fma chains so
// the compiler can emit v_fma_mix_f32 / cheap v_cvt_f32_f16.
// Centers read from LDS (same quantization as taps -> center diff exactly 0).
// Zero-fill halo == reference zero padding (s=0, v=0, coeff still enters den).

constexpr int H_ = 720;
constexpr int W_ = 1280;
constexpr int HW = H_ * W_;
constexpr float COEF0 = 0.875f;  // 1 - |NEG_SS_DIV|
constexpr float SIDIV = 50.0f;   // 1/(2*0.1^2)

constexpr int TC = 136;          // staged cols (gx0-4 .. gx0+131)
constexpr int TR = 12;           // staged rows (gy0-2 .. gy0+9)
constexpr int NCHUNK = 5 * TR * (TC / 4);   // 2040 4-half chunks; LDS byte = 8*i

struct alignas(8) H4 { __half h[4]; };      // one ds_write_b64 / ds_read_b64

__global__ __launch_bounds__(256, 8)
void jbf_h(const float* __restrict__ t, const float* __restrict__ v,
           float* __restrict__ out) {
    __shared__ __half lds[5][TR][TC];       // 16,320 B

    const int bx = blockIdx.x % 10;         // 10 x-tiles of 128
    const int by = (blockIdx.x / 10) % 90;  // 90 y-tiles of 8
    const int n  = blockIdx.x / 900;        // 2 images
    const int gx0 = bx * 128;
    const int gy0 = by * 8;

    const float* tn = t + (size_t)n * 3 * HW;
    const float* vn = v + (size_t)n * 2 * HW;
    float*       on = out + (size_t)n * 2 * HW;

    const int tid = threadIdx.x;

    // ---------------- stage tile into LDS as fp16 ----------------
#pragma unroll
    for (int it = 0; it < 8; ++it) {
        const int i = tid + it * 256;
        if (i < NCHUNK) {
            const int c4 = i % 34;           // 4-col chunk
            const int rr = (i / 34) % TR;    // staged row
            const int ch = i / (34 * TR);    // 0..2 = t, 3..4 = v
            const int gy = gy0 - 2 + rr;
            const int gx = gx0 - 4 + 4 * c4; // chunk all-in or all-out
            float4 val = make_float4(0.f, 0.f, 0.f, 0.f);
            if ((unsigned)gy < (unsigned)H_ && (unsigned)gx < (unsigned)(W_ - 3)) {
                const float* src = (ch < 3) ? (tn + (size_t)ch * HW)
                                            : (vn + (size_t)(ch - 3) * HW);
                val = *(const float4*)(src + gy * W_ + gx);
            }
            H4 hv;
            hv.h[0] = __float2half(val.x);
            hv.h[1] = __float2half(val.y);
            hv.h[2] = __float2half(val.z);
            hv.h[3] = __float2half(val.w);
            ((H4*)lds)[i] = hv;              // byte 8*i == &lds[ch][rr][4*c4]
        }
    }
    __syncthreads();

    // ---------------- compute 4 px from LDS ----------------
    const int tx = tid & 31;                 // x-group within tile
    const int ty = tid >> 5;                 // output row within tile
    const int lc = 4 * tx;                   // window base col (k=0 <-> col lc)

    // centers: staged row ty+2, cols lc+4..lc+7 (same quantization as taps)
    float c0f[4], c1f[4], c2f[4];
    {
        const H4 a = *(const H4*)&lds[0][ty + 2][lc + 4];
        const H4 b = *(const H4*)&lds[1][ty + 2][lc + 4];
        const H4 c = *(const H4*)&lds[2][ty + 2][lc + 4];
#pragma unroll
        for (int j = 0; j < 4; ++j) {
            c0f[j] = __half2float(a.h[j]);
            c1f[j] = __half2float(b.h[j]);
            c2f[j] = __half2float(c.h[j]);
        }
    }

    float num0[4] = {0.f, 0.f, 0.f, 0.f};
    float num1[4] = {0.f, 0.f, 0.f, 0.f};
    float den[4]  = {0.f, 0.f, 0.f, 0.f};

#pragma unroll 1
    for (int r = 0; r < 5; ++r) {
        const int lr = ty + r;
        __half w0[12], w1[12], w2[12], u0[12], u1[12];
#pragma unroll
        for (int s = 0; s < 3; ++s) {
            *(H4*)&w0[4 * s] = *(const H4*)&lds[0][lr][lc + 4 * s];
            *(H4*)&w1[4 * s] = *(const H4*)&lds[1][lr][lc + 4 * s];
            *(H4*)&w2[4 * s] = *(const H4*)&lds[2][lr][lc + 4 * s];
            *(H4*)&u0[4 * s] = *(const H4*)&lds[3][lr][lc + 4 * s];
            *(H4*)&u1[4 * s] = *(const H4*)&lds[4][lr][lc + 4 * s];
        }
#pragma unroll
        for (int dx = 0; dx < 5; ++dx) {
#pragma unroll
            for (int j = 0; j < 4; ++j) {
                const int k = dx + j + 2;    // compile-time index, k in [2,9]
                const float d0 = c0f[j] - __half2float(w0[k]);
                const float d1 = c1f[j] - __half2float(w1[k]);
                const float d2 = c2f[j] - __half2float(w2[k]);
                float diff = d0 * d0;
                diff = fmaf(d1, d1, diff);
                diff = fmaf(d2, d2, diff);
                const float c = fmaxf(fmaf(diff, -SIDIV, COEF0), 0.f);
                num0[j] = fmaf(__half2float(u0[k]), c, num0[j]);
                num1[j] = fmaf(__half2float(u1[k]), c, num1[j]);
                den[j] += c;
            }
        }
    }

    float4 o0, o1;
    float* o0a = (float*)&o0;
    float* o1a = (float*)&o1;
#pragma unroll
    for (int j = 0; j < 4; ++j) {
        const float rcp = 1.f / den[j];
        // mimic the reference's fp16 round-trip
        o0a[j] = __half2float(__float2half(num0[j] * rcp));
        o1a[j] = __half2float(__float2half(num1[j] * rcp));
    }
    const int ctr = (gy0 + ty) * W_ + gx0 + 4 * tx;
    *(float4*)(on + ctr) = o0;
    *(float4*)(on + HW + ctr) = o1;
}

extern "C" void kernel_launch(void* const* d_in, const int* in_sizes, int n_in,
                              void* d_out, int out_size, void* d_ws, size_t ws_size,
                              hipStream_t stream) {
    const float* t = (const float*)d_in[0];
    const float* v = (const float*)d_in[1];
    float* out = (float*)d_out;

    // 10 x-tiles * 90 y-tiles * 2 images = 1800 blocks of 256
    jbf_h<<<1800, 256, 0, stream>>>(t, v, out);
}